// Round 16
// baseline (17.299 us; speedup 1.0000x reference)
//
#include <hip/hip_runtime.h>

// EctLayer: ect[b,r,t] = sum_{n: batch[n]==b} sigmoid(SCALE*(lin[r] - (x[n]·dir[:,t])))
// N=65536, D=3, T=64, R=64, B=64. SCALE=500.
//
// Round-16: r15 + front-end latency cuts.
//  - parallel boundary windows: threads 0-255 scan the lo window, 256-511 the
//    hi window (r15 scanned them serially). Each thread covers 7 candidate
//    boundaries via two int4 loads (one latency exposure per window).
//  - vectorized x: one (4B-aligned) dwordx4 per lane-iteration instead of 3
//    dwords; last-point lane falls back to scalar (avoids 4B OOB read).
//  - XCD decode: b = bid&63, q = bid>>6 -> all 16 q-blocks of batch b share
//    bid%8 (same XCD) -> x range L2-cached once per XCD, not 16 cold misses.
//  - inner loop (r13): one packed ds_add_u32 (1<<20)|si at bin
//    j1=clamp(r0+1,0,64), si=round(sigmoid*2^9); skip upper-tail r0>=64.
//  - epilogue: wave 0 only; uint4 bins read, 6-step __shfl_up scan, float4
//    store. Analytic lo(0)=0 / hi(63)=N; full-sweep fallback only if a
//    sentinel survives (prob ~1e-9).
//  - errors: quant ~0.06, dropped tails <= ~0.2; threshold 19.44.

#define T_DIRS   64
#define R_STEPS  64
#define NROWS    65                     // bins 0..64
#define N_BATCH  64
#define TSPLIT   16
#define TQW      4                      // dirs per block
#define PSW      16                     // point slots per wave
#define THREADS  512
#define NWAVES   8
#define WIN      768                    // boundary search half-window (6 sigma)

#define RADIUS_F 1.1f
#define STEP_F   (2.0f * RADIUS_F / (R_STEPS - 1))          // 0.0349206
#define INV_STEP (1.0f / STEP_F)
#define OFF_F    (RADIUS_F * INV_STEP)                      // 31.5
#define MEXP     (-500.0f * STEP_F * 1.4426950408889634f)   // -K*log2(e)
#define FIXP     512.0f
#define INV_FIXP (1.0f / 512.0f)
#define CNT_ONE  (1u << 20)
#define SI_MASK  0xFFFFFu

typedef int   int4u __attribute__((ext_vector_type(4), aligned(4)));
typedef float f4u   __attribute__((ext_vector_type(4), aligned(4)));

__global__ __launch_bounds__(THREADS) void ect_kernel(
    const float* __restrict__ x,      // [N,3]
    const float* __restrict__ dirs,   // [3,T]
    const int*   __restrict__ batch,  // [N] sorted, values in [0,64)
    float* __restrict__ out,          // [B,R,T]
    int N)
{
    __shared__ unsigned s_a[NROWS * TQW];       // 1040 B packed bins
    __shared__ int      s_lo, s_hi;

    const int tid  = threadIdx.x;
    const int b    = blockIdx.x & 63;           // same-b blocks share bid%8 (XCD)
    const int q    = blockIdx.x >> 6;
    const int lane = tid & 63;
    const int w    = tid >> 6;
    const int ps   = lane >> 2;                 // point slot 0..15
    const int tq   = lane & (TQW - 1);          // local dir 0..3
    const int tg   = q * TQW + tq;              // global dir

    for (int i = tid; i < NROWS * TQW; i += THREADS) s_a[i] = 0u;
    if (tid == 0) {
        s_lo = (b == 0) ? 0 : -1;               // analytic: batch[j] >= 0
        s_hi = (b == N_BATCH - 1) ? N : -1;     // analytic: batch[j] <= 63
    }

    const float d0 = dirs[tg];
    const float d1 = dirs[T_DIRS + tg];
    const float d2 = dirs[2 * T_DIRS + tg];
    __syncthreads();

    // parallel windowed boundary scan: 7 candidates/thread, two int4 loads.
    // lo window: threads 0-255 around b*seg; hi window: 256-511 around (b+1)*seg.
    // In-bounds proof: c in [1024, 64512]; base = c-WIN-1+t7 in [255, 65528];
    // base+7 <= 65535 < N.
    {
        const int seg = N >> 6;                 // 1024
        const bool isLo = (tid < 256);
        const int  t2   = isLo ? tid : (tid - 256);
        const int  c    = (isLo ? b : (b + 1)) * seg;
        const bool run  = isLo ? (b != 0) : (b != N_BATCH - 1);
        if (run) {
            int base = c - WIN - 1 + t2 * 7;
            int4u ea = *(const int4u*)&batch[base];
            int4u eb = *(const int4u*)&batch[base + 4];
            int e[8] = {ea.x, ea.y, ea.z, ea.w, eb.x, eb.y, eb.z, eb.w};
#pragma unroll
            for (int i = 0; i < 7; ++i) {
                int j = base + 1 + i;
                if (j < c + WIN) {
                    if (isLo) { if (e[i+1] >= b && e[i] <  b) s_lo = j; }
                    else      { if (e[i+1] >  b && e[i] <= b) s_hi = j; }
                }
            }
        }
    }
    __syncthreads();

    // fallback: full coalesced sweep iff a sentinel survived (prob ~1e-9)
    if (s_lo < 0 || s_hi < 0) {
        for (int j = tid; j < N; j += THREADS) {
            int v  = batch[j];
            int vp = (j == 0) ? -1 : batch[j - 1];
            if (v >= b && vp < b)  s_lo = j;
            if (v >  b && vp <= b) s_hi = j;
        }
        __syncthreads();
    }
    const int lo  = (s_lo < 0) ? N : s_lo;
    const int hi  = (s_hi < 0) ? N : s_hi;
    const int len = hi - lo;
    const float* xb = x + (size_t)lo * 3;
    const int lastN = N - 1 - lo;               // p value of global last point

    // inner loop: one dwordx4 x-load per (lane, point); L2-resident
    for (int p = w * PSW + ps; p < len; p += NWAVES * PSW) {
        float x0, x1, x2;
        if (p != lastN) {
            f4u v = *(const f4u*)(xb + (size_t)p * 3);
            x0 = v.x; x1 = v.y; x2 = v.z;
        } else {                                // avoid 4B read past x[N-1]
            x0 = xb[p * 3]; x1 = xb[p * 3 + 1]; x2 = xb[p * 3 + 2];
        }
        float nh  = fmaf(x2, d2, fmaf(x1, d1, x0 * d0));
        float u   = fmaf(nh, INV_STEP, OFF_F);
        float r0f = rintf(u);
        float dd  = r0f - u;                               // [-0.5, 0.5]
        float e   = __builtin_amdgcn_exp2f(dd * MEXP);
        float s   = __builtin_amdgcn_rcpf(1.0f + e);       // sigmoid at r0
        unsigned si = (unsigned)fmaf(s, FIXP, 0.5f);       // [0, 2^9]
        int j1 = (int)r0f + 1;
        if (j1 <= R_STEPS) {                    // skip upper-tail trash
            j1 = max(j1, 0);
            atomicAdd(&s_a[j1 * TQW + tq], CNT_ONE | si);  // one ds_add_u32
        }
    }
    __syncthreads();
    if (w != 0) return;                         // single-wave epilogue

    uint4 rowv = *(const uint4*)&s_a[lane * TQW];          // ds_read_b128
    uint4 r64  = *(const uint4*)&s_a[R_STEPS * TQW];       // row 64 broadcast

    unsigned c0 = rowv.x >> 20, c1 = rowv.y >> 20,
             c2 = rowv.z >> 20, c3 = rowv.w >> 20;
    unsigned s0 = rowv.x & SI_MASK, s1 = rowv.y & SI_MASK,
             s2 = rowv.z & SI_MASK, s3 = rowv.w & SI_MASK;

    unsigned n0 = __shfl_down(s0, 1, 64), n1 = __shfl_down(s1, 1, 64),
             n2 = __shfl_down(s2, 1, 64), n3 = __shfl_down(s3, 1, 64);
    if (lane == 63) {
        n0 = r64.x & SI_MASK; n1 = r64.y & SI_MASK;
        n2 = r64.z & SI_MASK; n3 = r64.w & SI_MASK;
    }

#pragma unroll
    for (int d = 1; d < 64; d <<= 1) {
        unsigned u0 = __shfl_up(c0, d, 64), u1 = __shfl_up(c1, d, 64),
                 u2 = __shfl_up(c2, d, 64), u3 = __shfl_up(c3, d, 64);
        if (lane >= d) { c0 += u0; c1 += u1; c2 += u2; c3 += u3; }
    }

    float4 o;
    o.x = (float)c0 + (float)n0 * INV_FIXP;
    o.y = (float)c1 + (float)n1 * INV_FIXP;
    o.z = (float)c2 + (float)n2 * INV_FIXP;
    o.w = (float)c3 + (float)n3 * INV_FIXP;
    *(float4*)&out[((size_t)b << 12) | (lane << 6) | (q * TQW)] = o;
}

extern "C" void kernel_launch(void* const* d_in, const int* in_sizes, int n_in,
                              void* d_out, int out_size, void* d_ws, size_t ws_size,
                              hipStream_t stream) {
    const float* x     = (const float*)d_in[0];
    const float* dirs  = (const float*)d_in[1];
    const int*   batch = (const int*)d_in[3];
    float* out = (float*)d_out;
    const int N = in_sizes[3];

    ect_kernel<<<dim3(N_BATCH * TSPLIT), dim3(THREADS), 0, stream>>>(
        x, dirs, batch, out, N);
}

// Round 17
// 12.219 us; speedup vs baseline: 1.4158x; 1.4158x over previous
//
#include <hip/hip_runtime.h>

// EctLayer: ect[b,r,t] = sum_{n: batch[n]==b} sigmoid(SCALE*(lin[r] - (x[n]·dir[:,t])))
// N=65536, D=3, T=64, R=64, B=64. SCALE=500.
//
// Round-17: r15 base (12.12us) + ONE change: single-exposure boundary scan.
//  r15 scanned each window with 3 iters x 2 dependent scalar loads (~12
//  serial L2 latency exposures ~2-2.5us). Now every thread issues all 4
//  window loads (aligned int4 + guard scalar, lo & hi) back-to-back, then
//  compares: serial depth = 1 exposure. Window +-1024 (8 sigma, miss ~1e-15);
//  analytic lo(0)=0 / hi(63)=N; full-sweep fallback iff a sentinel survives.
//  Alignment: lob = b*1024 - 1024 + 4*tid == 0 (mod 4) -> int4 is 16B-aligned.
//  (r16 bundled 3 changes and regressed; all three reverted here.)
//  - inner loop (r13): one packed ds_add_u32 (1<<20)|si at bin
//    j1=clamp(r0+1,0,64), si=round(sigmoid*2^9); skip upper-tail r0>=64.
//    count=high 12 bits, si-sum=low 20 (len<2048 -> no overflow).
//  - epilogue: wave 0 only; uint4 LDS row read, 6-step __shfl_up inclusive
//    scan (4 dirs in parallel), one float4 store per lane.
//  - 1024 blocks = (batch b = bid>>4, q = bid&15) x 512 threads; disjoint
//    out[b,:,q*4..+4) slices; no global atomics, no memset, no pre/post
//    kernels; 3 hot-path syncs.
//  - errors: quant ~0.06, dropped tails <= ~0.2; threshold 19.44.

#define T_DIRS   64
#define R_STEPS  64
#define NROWS    65                     // bins 0..64
#define N_BATCH  64
#define TSPLIT   16
#define TQW      4                      // dirs per block
#define PSW      16                     // point slots per wave
#define THREADS  512
#define NWAVES   8

#define RADIUS_F 1.1f
#define STEP_F   (2.0f * RADIUS_F / (R_STEPS - 1))          // 0.0349206
#define INV_STEP (1.0f / STEP_F)
#define OFF_F    (RADIUS_F * INV_STEP)                      // 31.5
#define MEXP     (-500.0f * STEP_F * 1.4426950408889634f)   // -K*log2(e)
#define FIXP     512.0f
#define INV_FIXP (1.0f / 512.0f)
#define CNT_ONE  (1u << 20)
#define SI_MASK  0xFFFFFu

__global__ __launch_bounds__(THREADS) void ect_kernel(
    const float* __restrict__ x,      // [N,3]
    const float* __restrict__ dirs,   // [3,T]
    const int*   __restrict__ batch,  // [N] sorted, values in [0,64)
    float* __restrict__ out,          // [B,R,T]
    int N)
{
    __shared__ unsigned s_a[NROWS * TQW];       // 1040 B packed bins
    __shared__ int      s_lo, s_hi;

    const int tid  = threadIdx.x;
    const int b    = blockIdx.x >> 4;
    const int q    = blockIdx.x & (TSPLIT - 1);
    const int lane = tid & 63;
    const int w    = tid >> 6;
    const int ps   = lane >> 2;                 // point slot 0..15
    const int tq   = lane & (TQW - 1);          // local dir 0..3
    const int tg   = q * TQW + tq;              // global dir

    for (int i = tid; i < NROWS * TQW; i += THREADS) s_a[i] = 0u;
    if (tid == 0) {
        s_lo = (b == 0) ? 0 : -1;               // analytic: batch[j] >= 0
        s_hi = (b == N_BATCH - 1) ? N : -1;     // analytic: batch[j] <= 63
    }

    const float d0 = dirs[tg];
    const float d1 = dirs[T_DIRS + tg];
    const float d2 = dirs[2 * T_DIRS + tg];
    __syncthreads();

    // single-exposure boundary scan: 4 candidates per window per thread.
    // lo window: j in [clo-1024, clo+1024); hi window: same around chi.
    // All loads issued before any compare -> one latency exposure.
    {
        const int seg = N >> 6;                 // 1024
        const int clo = b * seg;
        const int chi = (b + 1) * seg;
        const bool doLo = (b != 0);
        const bool doHi = (b != N_BATCH - 1);   // uniform branches
        const int lob = clo - 1024 + 4 * tid;   // 16B-aligned (lob % 4 == 0)
        const int hib = chi - 1024 + 4 * tid;
        // bounds: doLo => b>=1 => lob in [0, 65532]; doHi => b<=62 => same.
        int4 elo, ehi;
        int  plo = -1, phi = -1;
        if (doLo) {
            elo = *(const int4*)&batch[lob];
            plo = (lob == 0) ? -1 : batch[lob - 1];
        }
        if (doHi) {
            ehi = *(const int4*)&batch[hib];
            phi = (hib == 0) ? -1 : batch[hib - 1];
        }
        if (doLo) {
            int v[5] = {plo, elo.x, elo.y, elo.z, elo.w};
#pragma unroll
            for (int i = 0; i < 4; ++i)
                if (v[i + 1] >= b && v[i] < b) s_lo = lob + i;
        }
        if (doHi) {
            int v[5] = {phi, ehi.x, ehi.y, ehi.z, ehi.w};
#pragma unroll
            for (int i = 0; i < 4; ++i)
                if (v[i + 1] > b && v[i] <= b) s_hi = hib + i;
        }
    }
    __syncthreads();

    // fallback: full coalesced sweep iff a sentinel survived (prob ~1e-15)
    if (s_lo < 0 || s_hi < 0) {
        for (int j = tid; j < N; j += THREADS) {
            int v  = batch[j];
            int vp = (j == 0) ? -1 : batch[j - 1];
            if (v >= b && vp < b)  s_lo = j;
            if (v >  b && vp <= b) s_hi = j;
        }
        __syncthreads();
    }
    const int lo  = (s_lo < 0) ? N : s_lo;      // still -1: segment empty
    const int hi  = (s_hi < 0) ? N : s_hi;      // still -1: tail reaches N
    const int len = hi - lo;
    const float* xb = x + (size_t)lo * 3;

    // inner loop: direct global x reads (L2-resident, 4-lane-uniform addr)
    for (int p = w * PSW + ps; p < len; p += NWAVES * PSW) {
        float x0 = xb[p * 3 + 0];
        float x1 = xb[p * 3 + 1];
        float x2 = xb[p * 3 + 2];
        float nh  = fmaf(x2, d2, fmaf(x1, d1, x0 * d0));
        float u   = fmaf(nh, INV_STEP, OFF_F);
        float r0f = rintf(u);
        float dd  = r0f - u;                               // [-0.5, 0.5]
        float e   = __builtin_amdgcn_exp2f(dd * MEXP);
        float s   = __builtin_amdgcn_rcpf(1.0f + e);       // sigmoid at r0
        unsigned si = (unsigned)fmaf(s, FIXP, 0.5f);       // [0, 2^9]
        int j1 = (int)r0f + 1;
        if (j1 <= R_STEPS) {                    // skip upper-tail trash
            j1 = max(j1, 0);
            atomicAdd(&s_a[j1 * TQW + tq], CNT_ONE | si);  // one ds_add_u32
        }
    }
    __syncthreads();
    if (w != 0) return;                         // single-wave epilogue

    // lane r handles output row r for the block's 4 dirs.
    uint4 rowv = *(const uint4*)&s_a[lane * TQW];          // ds_read_b128
    uint4 r64  = *(const uint4*)&s_a[R_STEPS * TQW];       // row 64 broadcast

    unsigned c0 = rowv.x >> 20, c1 = rowv.y >> 20,
             c2 = rowv.z >> 20, c3 = rowv.w >> 20;
    unsigned s0 = rowv.x & SI_MASK, s1 = rowv.y & SI_MASK,
             s2 = rowv.z & SI_MASK, s3 = rowv.w & SI_MASK;

    // si of row lane+1 (lane 63 takes row 64 directly)
    unsigned n0 = __shfl_down(s0, 1, 64), n1 = __shfl_down(s1, 1, 64),
             n2 = __shfl_down(s2, 1, 64), n3 = __shfl_down(s3, 1, 64);
    if (lane == 63) {
        n0 = r64.x & SI_MASK; n1 = r64.y & SI_MASK;
        n2 = r64.z & SI_MASK; n3 = r64.w & SI_MASK;
    }

    // 6-step inclusive scan over lanes (rows 0..63)
#pragma unroll
    for (int d = 1; d < 64; d <<= 1) {
        unsigned u0 = __shfl_up(c0, d, 64), u1 = __shfl_up(c1, d, 64),
                 u2 = __shfl_up(c2, d, 64), u3 = __shfl_up(c3, d, 64);
        if (lane >= d) { c0 += u0; c1 += u1; c2 += u2; c3 += u3; }
    }

    float4 o;
    o.x = (float)c0 + (float)n0 * INV_FIXP;
    o.y = (float)c1 + (float)n1 * INV_FIXP;
    o.z = (float)c2 + (float)n2 * INV_FIXP;
    o.w = (float)c3 + (float)n3 * INV_FIXP;
    *(float4*)&out[((size_t)b << 12) | (lane << 6) | (q * TQW)] = o;
}

extern "C" void kernel_launch(void* const* d_in, const int* in_sizes, int n_in,
                              void* d_out, int out_size, void* d_ws, size_t ws_size,
                              hipStream_t stream) {
    const float* x     = (const float*)d_in[0];
    const float* dirs  = (const float*)d_in[1];
    const int*   batch = (const int*)d_in[3];
    float* out = (float*)d_out;
    const int N = in_sizes[3];

    ect_kernel<<<dim3(N_BATCH * TSPLIT), dim3(THREADS), 0, stream>>>(
        x, dirs, batch, out, N);
}